// Round 6
// baseline (128.752 us; speedup 1.0000x reference)
//
#include <hip/hip_runtime.h>

#define IN_F 4096
#define OUT_F 4096
#define KGRP 16
#define N_ROWS (8 * 2048)
#define RPB 8                      // rows per block
#define NBLK (N_ROWS / RPB)        // 2048 blocks
#define WPARTS 32                  // wsum partial chunks

typedef float f32x4 __attribute__((ext_vector_type(4)));

// d_ws layout (16B-aligned):
//   [0,      32KB)   : wsum    double[4096]
//   [32KB,  1056KB)  : partial double[32][4096]

// ---------------------------------------------------------------------------
// Kernel 1a: partial column sums of weight. grid (16, 32) = 512 blocks.
// ---------------------------------------------------------------------------
__global__ __launch_bounds__(256) void wsum_partial_kernel(const float* __restrict__ w,
                                                           double* __restrict__ partial) {
    const int f = blockIdx.x * 256 + threadIdx.x;
    const int r0 = blockIdx.y * (OUT_F / WPARTS);
    const float* p = w + (size_t)r0 * IN_F + f;
    double s = 0.0;
#pragma unroll 16
    for (int o = 0; o < OUT_F / WPARTS; ++o) s += (double)p[(size_t)o * IN_F];
    partial[blockIdx.y * IN_F + f] = s;
}

// Kernel 1b: wsum[f] = sum over 32 partials.
__global__ __launch_bounds__(256) void wsum_reduce_kernel(const double* __restrict__ partial,
                                                          double* __restrict__ wsum) {
    const int f = blockIdx.x * 256 + threadIdx.x;
    double s = 0.0;
#pragma unroll
    for (int p = 0; p < WPARTS; ++p) s += partial[p * IN_F + f];
    wsum[f] = s;
}

// ---------------------------------------------------------------------------
// Kernel 2: FUSED read+compute+write. 2048 blocks x 8 rows.
// Per row: 4 NT float4 loads/thread -> f64 dot vs register-hoisted wsum ->
// folded 7-shfl butterfly (lanes 0-3 of each wave hold groups (l&3)*4+wave)
// -> g[r][16] in LDS -> one barrier -> ALL threads scan the 16 f64 group
// sums (same summation order as the passing R3/R5 kernels) -> sigmoid with
// register-hoisted bias -> 4 NT float4 stores. No second barrier needed
// (per-row g slot; next row touches a different slot).
// ---------------------------------------------------------------------------
__global__ __launch_bounds__(256) void fused_kernel(const float* __restrict__ x,
                                                    const double* __restrict__ wsum,
                                                    const float* __restrict__ bias,
                                                    float* __restrict__ out) {
    const int t = threadIdx.x;
    const int lane = t & 63;
    const int wave = t >> 6;
    const int n0 = blockIdx.x * RPB;

    __shared__ double g[RPB][KGRP];

    double wreg[16];
#pragma unroll
    for (int k = 0; k < 4; ++k) {
        const double* wp = &wsum[4 * (k * 256 + t)];
        double2 w01 = *(const double2*)(wp);
        double2 w23 = *(const double2*)(wp + 2);
        wreg[4 * k + 0] = w01.x; wreg[4 * k + 1] = w01.y;
        wreg[4 * k + 2] = w23.x; wreg[4 * k + 3] = w23.y;
    }

    const f32x4* b4 = (const f32x4*)bias;
    f32x4 b[4];
#pragma unroll
    for (int k = 0; k < 4; ++k) b[k] = b4[k * 256 + t];

#pragma unroll
    for (int r = 0; r < RPB; ++r) {
        const f32x4* xr = (const f32x4*)(x + (size_t)(n0 + r) * IN_F);
        double part[4];
#pragma unroll
        for (int k = 0; k < 4; ++k) {
            f32x4 v = __builtin_nontemporal_load(&xr[k * 256 + t]);
            part[k] = (double)v.x * wreg[4 * k + 0] + (double)v.y * wreg[4 * k + 1] +
                      (double)v.z * wreg[4 * k + 2] + (double)v.w * wreg[4 * k + 3];
        }
        // folded butterfly: 4 values over 64 lanes in 7 shfls
        {
            double keep01 = (lane & 1) ? part[1] : part[0];
            double send01 = (lane & 1) ? part[0] : part[1];
            double keep23 = (lane & 1) ? part[3] : part[2];
            double send23 = (lane & 1) ? part[2] : part[3];
            double w01 = keep01 + __shfl_xor(send01, 1, 64);
            double w23 = keep23 + __shfl_xor(send23, 2 - 1, 64);  // xor 1
            double keep = (lane & 2) ? w23 : w01;
            double send = (lane & 2) ? w01 : w23;
            double rv = keep + __shfl_xor(send, 2, 64);
#pragma unroll
            for (int off = 4; off <= 32; off <<= 1)
                rv += __shfl_xor(rv, off, 64);
            if (lane < 4) g[r][lane * 4 + wave] = rv;
        }
        __syncthreads();

        // all threads redundantly scan the 16 group sums (f64, exact order)
        double cs = 0.0, Sv = 0.0;
        bool found = false;
#pragma unroll
        for (int k = 0; k < KGRP; ++k) {
            cs += g[r][k];
            if (!found && cs >= 0.0) { Sv = cs; found = true; }
        }
        if (!found) Sv = cs;
        const float S = (float)Sv;

        f32x4* o4 = (f32x4*)(out + (size_t)(n0 + r) * OUT_F);
#pragma unroll
        for (int k = 0; k < 4; ++k) {
            f32x4 rr;
            rr.x = __builtin_amdgcn_rcpf(1.0f + __expf(-(S + b[k].x)));
            rr.y = __builtin_amdgcn_rcpf(1.0f + __expf(-(S + b[k].y)));
            rr.z = __builtin_amdgcn_rcpf(1.0f + __expf(-(S + b[k].z)));
            rr.w = __builtin_amdgcn_rcpf(1.0f + __expf(-(S + b[k].w)));
            __builtin_nontemporal_store(rr, &o4[k * 256 + t]);
        }
    }
}

extern "C" void kernel_launch(void* const* d_in, const int* in_sizes, int n_in,
                              void* d_out, int out_size, void* d_ws, size_t ws_size,
                              hipStream_t stream) {
    const float* x    = (const float*)d_in[0];   // [8,2048,4096] f32
    const float* w    = (const float*)d_in[1];   // [4096,4096]   f32
    const float* bias = (const float*)d_in[2];   // [4096]        f32
    float* out = (float*)d_out;                  // [8,2048,4096] f32

    char* ws = (char*)d_ws;
    double* wsum    = (double*)(ws);                 // 4096 doubles
    double* partial = (double*)(ws + 32 * 1024);     // 32*4096 doubles

    dim3 g1(IN_F / 256, WPARTS);
    wsum_partial_kernel<<<g1, 256, 0, stream>>>(w, partial);
    wsum_reduce_kernel<<<IN_F / 256, 256, 0, stream>>>(partial, wsum);
    fused_kernel<<<NBLK, 256, 0, stream>>>(x, wsum, bias, out);
}